// Round 1
// baseline (2129.672 us; speedup 1.0000x reference)
//
#include <hip/hip_runtime.h>
#include <math.h>

#define HH 256
#define WW 256
#define HWs 65536
#define DIMc 64
#define RK 32

__device__ inline float dot64(const float* __restrict__ w, const float* v) {
    const float4* w4 = (const float4*)w;
    float a = 0.f;
#pragma unroll
    for (int i = 0; i < 16; ++i) {
        float4 ww = w4[i];
        a += ww.x * v[4*i] + ww.y * v[4*i+1] + ww.z * v[4*i+2] + ww.w * v[4*i+3];
    }
    return a;
}
__device__ inline float dot32(const float* __restrict__ w, const float* v) {
    const float4* w4 = (const float4*)w;
    float a = 0.f;
#pragma unroll
    for (int i = 0; i < 8; ++i) {
        float4 ww = w4[i];
        a += ww.x * v[4*i] + ww.y * v[4*i+1] + ww.z * v[4*i+2] + ww.w * v[4*i+3];
    }
    return a;
}

// K1: per-pixel router + pointwise preprojections, expert weights staged in LDS.
__global__ __launch_bounds__(256) void k_router(
    const float* __restrict__ x,
    const float* __restrict__ rw, const float* __restrict__ rb,
    const float* __restrict__ p0w, const float* __restrict__ qw, const float* __restrict__ kvw,
    int* __restrict__ eIdx, float* __restrict__ gVal,
    float* __restrict__ qpre, float* __restrict__ kvpre)
{
    // phase A: rw[256] @0, p0w[8192] @256, qw[4096] @8448
    // phase B: kvw[8192] @0
    __shared__ float wl[12544];
    const int tid = threadIdx.x;
    const int p = blockIdx.x * 256 + tid;   // [0, B*HW)
    const int b = p >> 16;
    const int hw = p & 0xFFFF;

    for (int i = tid; i < 256;  i += 256) wl[i] = rw[i];
    for (int i = tid; i < 8192; i += 256) wl[256 + i] = p0w[i];
    for (int i = tid; i < 4096; i += 256) wl[8448 + i] = qw[i];
    __syncthreads();

    const float* xb = x + ((size_t)b * DIMc) * HWs + hw;
    float xr[DIMc];
#pragma unroll
    for (int c = 0; c < DIMc; ++c) xr[c] = xb[(size_t)c * HWs];

    float l[4];
#pragma unroll
    for (int e = 0; e < 4; ++e) l[e] = rb[e] + dot64(&wl[e * DIMc], xr);

    float m = fmaxf(fmaxf(l[0], l[1]), fmaxf(l[2], l[3]));
    int e = (l[0] == m) ? 0 : (l[1] == m) ? 1 : (l[2] == m) ? 2 : 3;
    float s = expf(l[0]-m) + expf(l[1]-m) + expf(l[2]-m) + expf(l[3]-m);
    float g = 1.0f / s;
    eIdx[p] = e;
    gVal[p] = g;

    float h1[RK];
    const float* w0 = &wl[256 + e * RK * DIMc];
#pragma unroll
    for (int r = 0; r < RK; ++r) h1[r] = g * dot64(&w0[r * DIMc], xr);

    const float* wq = &wl[8448 + e * RK * RK];
#pragma unroll
    for (int r = 0; r < RK; ++r)
        qpre[((size_t)(b * RK + r)) * HWs + hw] = dot32(&wq[r * RK], h1);

    __syncthreads();
    for (int i = tid; i < 8192; i += 256) wl[i] = kvw[i];
    __syncthreads();

    const float* wk = &wl[e * 2 * RK * RK];
#pragma unroll
    for (int r = 0; r < 2 * RK; ++r)
        kvpre[((size_t)(b * 2 * RK + r)) * HWs + hw] = dot32(&wk[r * RK], h1);
}

// K2: one 256-thread block per 8x8 patch; 4 channels in flight (cq = tid>>6).
// LDS layout (total 40848 B -> 4 blocks/CU):
//   pool[5960] floats (16B aligned):
//     kvh   @0     : 4cq x 210 float2 (14x14 halo, stride 15; .x=k, .y=v)
//     qh    @1680  : 4cq x 110 (10x10, stride 11)
//     qA    @2120  : 4cq x [4 experts x 65]   (stride 65 -> expert bank offset +1)
//     kA    @3160  : 4cq x [4 experts x 68]   (stride 68 -> 16B aligned + bank offset +4)
//     wq3   @4248  : 4cq x 36
//     wkv7  @4392  : 4cq x 196 float2 (.x=wk, .y=wv)
//   epilogue aliases: svS=pool[0..4160) stride 65; combS=pool; uS=oOwn.
//   oOwn[64*33], vOwn[64*33], ehP[14] u64 (4-bit codes expert+1, 0=outside)
__global__ __launch_bounds__(256) void k_patch(
    const float* __restrict__ x, const float* __restrict__ shr,
    const int* __restrict__ eIdx, const float* __restrict__ gVal,
    const float* __restrict__ qpre, const float* __restrict__ kvpre,
    const float* __restrict__ p1w,
    const float* __restrict__ qdw, const float* __restrict__ qdb,
    const float* __restrict__ kvdw, const float* __restrict__ kvdb,
    const float* __restrict__ lnw, const float* __restrict__ lnb,
    const float* __restrict__ fpw, const float* __restrict__ fpb,
    const float* __restrict__ p2w,
    const float* __restrict__ outw, const float* __restrict__ outb,
    float* __restrict__ out)
{
    __shared__ __align__(16) float pool[5960];
    __shared__ float oOwn[64 * 33];
    __shared__ float vOwn[64 * 33];
    __shared__ unsigned long long ehP[14];

    const int tid = threadIdx.x;
    const int cq = tid >> 6;
    const int t  = tid & 63;
    const int bid = blockIdx.x;
    const int b  = bid >> 10;
    const int pp = bid & 1023;
    const int py = pp >> 5, px = pp & 31;
    const int y0 = py * 8, x0 = px * 8;
    const int ly = t >> 3, lx = t & 7;
    const int gy = y0 + ly, gx = x0 + lx;
    const int hw = gy * WW + gx;
    const size_t base = (size_t)b * HWs;

    // ---- build packed expert halo: 4-bit code per halo cell, code = expert+1 (0 = outside) ----
    unsigned int* ehW = (unsigned int*)ehP;
    if (tid < 28) ehW[tid] = 0u;
    __syncthreads();
    for (int j = tid; j < 196; j += 256) {
        int r = j / 14, cc = j % 14;
        int yy = y0 - 3 + r, xx = x0 - 3 + cc;
        if ((unsigned)yy < HH && (unsigned)xx < WW) {
            unsigned int code = (unsigned)eIdx[base + yy * WW + xx] + 1u;
            atomicOr(&ehW[r * 2 + (cc >> 3)], code << ((cc & 7) * 4));
        }
    }
    __syncthreads();

    // hoist this lane's 7 halo rows into registers (rows ly..ly+6 cover dw7 and dw3)
    unsigned long long Eh[7];
#pragma unroll
    for (int i = 0; i < 7; ++i) Eh[i] = ehP[ly + i];
    const int ep = (int)((Eh[3] >> ((lx + 3) * 4)) & 15ull) - 1;   // own expert (always in range)

    float2* kvS  = (float2*)pool + cq * 210;
    float*  qhS  = pool + 1680 + cq * 110;
    float*  qAS  = pool + 2120 + cq * 260;
    float*  kAS  = pool + 3160 + cq * 272;
    float*  wq3S = pool + 4248 + cq * 36;
    float2* wkvS = (float2*)(pool + 4392) + cq * 196;

    for (int ch = 0; ch < 8; ++ch) {
        const int c = ch * 4 + cq;
        // ---- stage planes + weights for this channel ----
        for (int j = t; j < 196; j += 64) {
            int r = j / 14, cc = j % 14;
            int yy = y0 - 3 + r, xx = x0 - 3 + cc;
            float kv_ = 0.f, vv_ = 0.f;
            if ((unsigned)yy < HH && (unsigned)xx < WW) {
                size_t o1 = ((size_t)(b * 64 + c)) * HWs + yy * WW + xx;
                kv_ = kvpre[o1];
                vv_ = kvpre[o1 + (size_t)32 * HWs];
            }
            kvS[r * 15 + cc] = make_float2(kv_, vv_);
        }
        for (int j = t; j < 100; j += 64) {
            int r = j / 10, cc = j % 10;
            int yy = y0 - 1 + r, xx = x0 - 1 + cc;
            float qv = 0.f;
            if ((unsigned)yy < HH && (unsigned)xx < WW)
                qv = qpre[((size_t)(b * RK + c)) * HWs + yy * WW + xx];
            qhS[r * 11 + cc] = qv;
        }
        if (t < 36) wq3S[t] = qdw[(t / 9) * RK * 9 + c * 9 + (t % 9)];
        for (int j = t; j < 196; j += 64) {
            int i = j / 49, kk2 = j % 49;
            wkvS[j] = make_float2(kvdw[((size_t)(i * 64 + c)) * 49 + kk2],
                                  kvdw[((size_t)(i * 64 + 32 + c)) * 49 + kk2]);
        }
        __syncthreads();

        // ---- dw3: q for all experts at this pixel (halo origin -1 -> code row offset +2) ----
        float qa0 = qdb[0*RK+c], qa1 = qdb[1*RK+c], qa2 = qdb[2*RK+c], qa3 = qdb[3*RK+c];
#pragma unroll
        for (int dy = 0; dy < 3; ++dy) {
            const unsigned long long E = Eh[dy + 2];
            const int rq = (ly + dy) * 11 + lx;
#pragma unroll
            for (int dx = 0; dx < 3; ++dx) {
                int code = (int)((E >> ((lx + dx + 2) * 4)) & 15ull);
                if (code) {
                    int ie = code - 1;
                    float wv = wq3S[ie * 9 + dy * 3 + dx] * qhS[rq + dx];
                    qa0 += (ie == 0) ? wv : 0.f;
                    qa1 += (ie == 1) ? wv : 0.f;
                    qa2 += (ie == 2) ? wv : 0.f;
                    qa3 += (ie == 3) ? wv : 0.f;
                }
            }
        }
        qAS[0*65+t] = qa0; qAS[1*65+t] = qa1; qAS[2*65+t] = qa2; qAS[3*65+t] = qa3;

        // ---- dw7: k for all experts, v for own expert (k+v fused in one b64 read) ----
        float ka0 = kvdb[0*64+c], ka1 = kvdb[1*64+c], ka2 = kvdb[2*64+c], ka3 = kvdb[3*64+c];
        float va = kvdb[ep * 64 + 32 + c];
#pragma unroll
        for (int dy = 0; dy < 7; ++dy) {
            const unsigned long long E = Eh[dy];
            const int rk = (ly + dy) * 15 + lx;
#pragma unroll
            for (int dx = 0; dx < 7; ++dx) {
                int code = (int)((E >> ((lx + dx) * 4)) & 15ull);
                if (code) {
                    int ie = code - 1;
                    float2 kv = kvS[rk + dx];
                    float2 w2 = wkvS[ie * 49 + dy * 7 + dx];
                    float wv = w2.x * kv.x;
                    ka0 += (ie == 0) ? wv : 0.f;
                    ka1 += (ie == 1) ? wv : 0.f;
                    ka2 += (ie == 2) ? wv : 0.f;
                    ka3 += (ie == 3) ? wv : 0.f;
                    va  += (ie == ep) ? w2.y * kv.y : 0.f;
                }
            }
        }
        kAS[0*68+t] = ka0; kAS[1*68+t] = ka1; kAS[2*68+t] = ka2; kAS[3*68+t] = ka3;
        vOwn[t * 33 + c] = va;
        __syncthreads();

        // ---- 8x8 circular convolution, own expert ----
        // oc = sum_{sy,sx} q[sy*8+sx] * k[((ly-sy)&7)*8 + ((lx-sx)&7)]
        // substituted u=(lx-sx)&7: k row loaded as 2x b128 (compile-time kk[u]),
        // q read per-lane b32 at offsets ((lx-u)&7), imm-offset sy*32.
        const float* qrow = pool + 2120 + cq * 260 + ep * 65;
        const float* krow = pool + 3160 + cq * 272 + ep * 68;
        float oc = 0.f;
#pragma unroll
        for (int sy = 0; sy < 8; ++sy) {
            const float4* k4 = (const float4*)(krow + ((ly - sy) & 7) * 8);
            float4 ka = k4[0], kb = k4[1];
            const float* qb = qrow + sy * 8;
            oc += qb[ lx      & 7] * ka.x;
            oc += qb[(lx - 1) & 7] * ka.y;
            oc += qb[(lx - 2) & 7] * ka.z;
            oc += qb[(lx - 3) & 7] * ka.w;
            oc += qb[(lx - 4) & 7] * kb.x;
            oc += qb[(lx - 5) & 7] * kb.y;
            oc += qb[(lx - 6) & 7] * kb.z;
            oc += qb[(lx - 7) & 7] * kb.w;
        }
        oOwn[t * 33 + c] = oc;
        __syncthreads();
    }

    // ---- epilogue, parallel over cq ----
    float* svS   = pool;        // [pix][65]
    float* uS    = oOwn;        // [pix][33]  (oOwn dead after o_ regs loaded)
    float* combS = pool;        // [pix][65]  (aliases svS after it is dead)

    for (int j = tid; j < 64 * 64; j += 256) {
        int c = j >> 6, pix = j & 63;
        int phw = (y0 + (pix >> 3)) * WW + x0 + (pix & 7);
        svS[pix * 65 + c] = shr[((size_t)(b * 64 + c)) * HWs + phw];
    }

    float o_[RK], vv_[RK];
#pragma unroll
    for (int c = 0; c < RK; ++c) { o_[c] = oOwn[t * 33 + c]; vv_[c] = vOwn[t * 33 + c]; }
    float mu = 0.f;
#pragma unroll
    for (int c = 0; c < RK; ++c) mu += o_[c];
    mu *= (1.0f / RK);
    float var = 0.f;
#pragma unroll
    for (int c = 0; c < RK; ++c) { float d = o_[c] - mu; var += d * d; }
    var *= (1.0f / RK);
    float inv = 1.0f / sqrtf(var + 1e-5f);
    float ttv[RK];
#pragma unroll
    for (int c = 0; c < RK; ++c)
        ttv[c] = ((o_[c] - mu) * inv * lnw[ep * RK + c] + lnb[ep * RK + c]) * vv_[c];

    const float g = gVal[base + hw];
    __syncthreads();   // svS ready, oOwn reads done

    // u rows r = cq*8 .. cq*8+7
    for (int r8 = 0; r8 < 8; ++r8) {
        int r = cq * 8 + r8;
        const float* wp1 = &p1w[(size_t)(ep * RK + r) * DIMc];
        float z = 0.f;
#pragma unroll
        for (int c = 0; c < DIMc; ++c) z += wp1[c] * svS[t * 65 + c];
        z *= g;
        float gate = z / (1.f + expf(-z));
        float bdy = fpb[ep * RK + r] + dot32(&fpw[(size_t)(ep * RK + r) * RK], ttv);
        uS[t * 33 + r] = bdy * gate;
    }
    __syncthreads();   // uS ready, svS dead

    // comb channels oo = cq*16 .. +15
    for (int o16 = 0; o16 < 16; ++o16) {
        int oo = cq * 16 + o16;
        const float* wp2 = &p2w[(size_t)(ep * DIMc + oo) * RK];
        float a = 0.f;
#pragma unroll
        for (int r = 0; r < RK; ++r) a += wp2[r] * uS[t * 33 + r];
        float xv = x[((size_t)(b * DIMc + oo)) * HWs + hw];
        combS[t * 65 + oo] = g * a + g * g * xv;
    }
    __syncthreads();   // combS ready

    for (int o16 = 0; o16 < 16; ++o16) {
        int oo = cq * 16 + o16;
        const float* wo = &outw[oo * DIMc];
        float a = outb[oo];
#pragma unroll
        for (int c = 0; c < DIMc; ++c) a += wo[c] * combS[t * 65 + c];
        out[((size_t)(b * DIMc + oo)) * HWs + hw] = a;
    }
}

extern "C" void kernel_launch(void* const* d_in, const int* in_sizes, int n_in,
                              void* d_out, int out_size, void* d_ws, size_t ws_size,
                              hipStream_t stream) {
    const float* x    = (const float*)d_in[0];
    const float* shr  = (const float*)d_in[1];
    const float* rw   = (const float*)d_in[2];
    const float* rb_  = (const float*)d_in[3];
    const float* p0w  = (const float*)d_in[4];
    const float* p1w  = (const float*)d_in[5];
    const float* p2w  = (const float*)d_in[6];
    const float* qw   = (const float*)d_in[7];
    const float* qdw  = (const float*)d_in[8];
    const float* qdb  = (const float*)d_in[9];
    const float* kvw  = (const float*)d_in[10];
    const float* kvdw = (const float*)d_in[11];
    const float* kvdb = (const float*)d_in[12];
    const float* lnw  = (const float*)d_in[13];
    const float* lnb  = (const float*)d_in[14];
    const float* fpw  = (const float*)d_in[15];
    const float* fpb  = (const float*)d_in[16];
    const float* outw = (const float*)d_in[17];
    const float* outb = (const float*)d_in[18];
    float* out = (float*)d_out;

    const int N = 4 * HWs;
    char* ws = (char*)d_ws;
    int*   eIdx  = (int*)ws;            ws += (size_t)N * sizeof(int);
    float* gV    = (float*)ws;          ws += (size_t)N * sizeof(float);
    float* qpre  = (float*)ws;          ws += (size_t)N * RK * sizeof(float);
    float* kvpre = (float*)ws;          ws += (size_t)N * 2 * RK * sizeof(float);

    k_router<<<N / 256, 256, 0, stream>>>(x, rw, rb_, p0w, qw, kvw, eIdx, gV, qpre, kvpre);
    k_patch<<<4 * 32 * 32, 256, 0, stream>>>(x, shr, eIdx, gV, qpre, kvpre,
                                             p1w, qdw, qdb, kvdw, kvdb,
                                             lnw, lnb, fpw, fpb, p2w, outw, outb, out);
}

// Round 2
// 1738.778 us; speedup vs baseline: 1.2248x; 1.2248x over previous
//
#include <hip/hip_runtime.h>
#include <math.h>

#define HH 256
#define WW 256
#define HWs 65536
#define DIMc 64
#define RK 32

__device__ inline float dot64(const float* __restrict__ w, const float* v) {
    const float4* w4 = (const float4*)w;
    float a = 0.f;
#pragma unroll
    for (int i = 0; i < 16; ++i) {
        float4 ww = w4[i];
        a += ww.x * v[4*i] + ww.y * v[4*i+1] + ww.z * v[4*i+2] + ww.w * v[4*i+3];
    }
    return a;
}
__device__ inline float dot32(const float* __restrict__ w, const float* v) {
    const float4* w4 = (const float4*)w;
    float a = 0.f;
#pragma unroll
    for (int i = 0; i < 8; ++i) {
        float4 ww = w4[i];
        a += ww.x * v[4*i] + ww.y * v[4*i+1] + ww.z * v[4*i+2] + ww.w * v[4*i+3];
    }
    return a;
}

// K1: per-pixel router + pointwise preprojections, expert weights staged in LDS.
__global__ __launch_bounds__(256) void k_router(
    const float* __restrict__ x,
    const float* __restrict__ rw, const float* __restrict__ rb,
    const float* __restrict__ p0w, const float* __restrict__ qw, const float* __restrict__ kvw,
    int* __restrict__ eIdx, float* __restrict__ gVal,
    float* __restrict__ qpre, float* __restrict__ kvpre)
{
    __shared__ float wl[12544];
    const int tid = threadIdx.x;
    const int p = blockIdx.x * 256 + tid;   // [0, B*HW)
    const int b = p >> 16;
    const int hw = p & 0xFFFF;

    for (int i = tid; i < 256;  i += 256) wl[i] = rw[i];
    for (int i = tid; i < 8192; i += 256) wl[256 + i] = p0w[i];
    for (int i = tid; i < 4096; i += 256) wl[8448 + i] = qw[i];
    __syncthreads();

    const float* xb = x + ((size_t)b * DIMc) * HWs + hw;
    float xr[DIMc];
#pragma unroll
    for (int c = 0; c < DIMc; ++c) xr[c] = xb[(size_t)c * HWs];

    float l[4];
#pragma unroll
    for (int e = 0; e < 4; ++e) l[e] = rb[e] + dot64(&wl[e * DIMc], xr);

    float m = fmaxf(fmaxf(l[0], l[1]), fmaxf(l[2], l[3]));
    int e = (l[0] == m) ? 0 : (l[1] == m) ? 1 : (l[2] == m) ? 2 : 3;
    float s = expf(l[0]-m) + expf(l[1]-m) + expf(l[2]-m) + expf(l[3]-m);
    float g = 1.0f / s;
    eIdx[p] = e;
    gVal[p] = g;

    float h1[RK];
    const float* w0 = &wl[256 + e * RK * DIMc];
#pragma unroll
    for (int r = 0; r < RK; ++r) h1[r] = g * dot64(&w0[r * DIMc], xr);

    const float* wq = &wl[8448 + e * RK * RK];
#pragma unroll
    for (int r = 0; r < RK; ++r)
        qpre[((size_t)(b * RK + r)) * HWs + hw] = dot32(&wq[r * RK], h1);

    __syncthreads();
    for (int i = tid; i < 8192; i += 256) wl[i] = kvw[i];
    __syncthreads();

    const float* wk = &wl[e * 2 * RK * RK];
#pragma unroll
    for (int r = 0; r < 2 * RK; ++r)
        kvpre[((size_t)(b * 2 * RK + r)) * HWs + hw] = dot32(&wk[r * RK], h1);
}

// K2: one 256-thread block per 8x8 patch; 4 channels in flight (cq = tid>>6).
// LDS total 40432 B -> LDS_Block_Size 40448 -> 4 blocks/CU (VGPR pinned <=128).
// pool[5856] floats, main-loop layout per cq:
//   kh   @0    : 4 x 210 (14x14, stride 15)
//   vh   @840  : 4 x 210
//   qh   @1680 : 4 x 100 (10x10, stride 10)
//   qA   @2080 : 4 x [4 experts x 65]  (stride 65: expert bank offset +1, kills 4-way q conflict)
//   kA   @3120 : 4 x [4 experts x 64]  (stride 64: offsets alone give exact 2 lanes/bank = free)
//   wq3  @4144 : 4 x 36
//   wkv7 @4288 : 4 x 196 float2 (.x=wk, .y=wv; ie-broadcast reads are conflict-free)
// epilogue aliases: svS/combS = pool [pix][65]; uS = oOwn (dead by then).
// ehP[14] u64: 4-bit code per halo cell (expert+1, 0=outside), one b64 broadcast per dy row.
__global__ __launch_bounds__(256, 4) void k_patch(
    const float* __restrict__ x, const float* __restrict__ shr,
    const int* __restrict__ eIdx, const float* __restrict__ gVal,
    const float* __restrict__ qpre, const float* __restrict__ kvpre,
    const float* __restrict__ p1w,
    const float* __restrict__ qdw, const float* __restrict__ qdb,
    const float* __restrict__ kvdw, const float* __restrict__ kvdb,
    const float* __restrict__ lnw, const float* __restrict__ lnb,
    const float* __restrict__ fpw, const float* __restrict__ fpb,
    const float* __restrict__ p2w,
    const float* __restrict__ outw, const float* __restrict__ outb,
    float* __restrict__ out)
{
    __shared__ __align__(16) float pool[5856];
    __shared__ float oOwn[64 * 33];
    __shared__ float vOwn[64 * 33];
    __shared__ unsigned long long ehP[14];

    const int tid = threadIdx.x;
    const int cq = tid >> 6;
    const int t  = tid & 63;
    const int bid = blockIdx.x;
    const int b  = bid >> 10;
    const int pp = bid & 1023;
    const int py = pp >> 5, px = pp & 31;
    const int y0 = py * 8, x0 = px * 8;
    const int ly = t >> 3, lx = t & 7;
    const int gy = y0 + ly, gx = x0 + lx;
    const int hw = gy * WW + gx;
    const size_t base = (size_t)b * HWs;

    // ---- build packed expert halo ----
    unsigned int* ehW = (unsigned int*)ehP;
    if (tid < 28) ehW[tid] = 0u;
    __syncthreads();
    for (int j = tid; j < 196; j += 256) {
        int r = j / 14, cc = j % 14;
        int yy = y0 - 3 + r, xx = x0 - 3 + cc;
        if ((unsigned)yy < HH && (unsigned)xx < WW) {
            unsigned int code = (unsigned)eIdx[base + yy * WW + xx] + 1u;
            atomicOr(&ehW[r * 2 + (cc >> 3)], code << ((cc & 7) * 4));
        }
    }
    __syncthreads();
    const int ep = (int)((ehP[ly + 3] >> ((lx + 3) * 4)) & 15ull) - 1;

    float*  khS  = pool + cq * 210;
    float*  vhS  = pool + 840 + cq * 210;
    float*  qhS  = pool + 1680 + cq * 100;
    float*  qAS  = pool + 2080 + cq * 260;
    float*  kAS  = pool + 3120 + cq * 256;
    float*  wq3S = pool + 4144 + cq * 36;
    float2* wkvS = (float2*)(pool + 4288) + cq * 196;

    for (int ch = 0; ch < 8; ++ch) {
        const int c = ch * 4 + cq;
        // ---- stage planes + weights for this channel ----
        for (int j = t; j < 196; j += 64) {
            int r = j / 14, cc = j % 14;
            int yy = y0 - 3 + r, xx = x0 - 3 + cc;
            float kv_ = 0.f, vv_ = 0.f;
            if ((unsigned)yy < HH && (unsigned)xx < WW) {
                size_t o1 = ((size_t)(b * 64 + c)) * HWs + yy * WW + xx;
                kv_ = kvpre[o1];
                vv_ = kvpre[o1 + (size_t)32 * HWs];
            }
            khS[r * 15 + cc] = kv_;
            vhS[r * 15 + cc] = vv_;
        }
        for (int j = t; j < 100; j += 64) {
            int r = j / 10, cc = j % 10;
            int yy = y0 - 1 + r, xx = x0 - 1 + cc;
            float qv = 0.f;
            if ((unsigned)yy < HH && (unsigned)xx < WW)
                qv = qpre[((size_t)(b * RK + c)) * HWs + yy * WW + xx];
            qhS[r * 10 + cc] = qv;
        }
        if (t < 36) wq3S[t] = qdw[(t / 9) * RK * 9 + c * 9 + (t % 9)];
        for (int j = t; j < 196; j += 64) {
            int i = j / 49, kk2 = j % 49;
            wkvS[j] = make_float2(kvdw[((size_t)(i * 64 + c)) * 49 + kk2],
                                  kvdw[((size_t)(i * 64 + 32 + c)) * 49 + kk2]);
        }
        __syncthreads();

        // ---- dw3: q for all experts at this pixel (code col offset +2, row offset +2) ----
        float qa0 = qdb[0*RK+c], qa1 = qdb[1*RK+c], qa2 = qdb[2*RK+c], qa3 = qdb[3*RK+c];
#pragma unroll
        for (int dy = 0; dy < 3; ++dy) {
            const unsigned long long E = ehP[ly + dy + 2];
            const int rq = (ly + dy) * 10 + lx;
#pragma unroll
            for (int dx = 0; dx < 3; ++dx) {
                int code = (int)((E >> ((lx + dx + 2) * 4)) & 15ull);
                if (code) {
                    int ie = code - 1;
                    float wv = wq3S[ie * 9 + dy * 3 + dx] * qhS[rq + dx];
                    qa0 += (ie == 0) ? wv : 0.f;
                    qa1 += (ie == 1) ? wv : 0.f;
                    qa2 += (ie == 2) ? wv : 0.f;
                    qa3 += (ie == 3) ? wv : 0.f;
                }
            }
        }
        qAS[0*65+t] = qa0; qAS[1*65+t] = qa1; qAS[2*65+t] = qa2; qAS[3*65+t] = qa3;

        // ---- dw7: k for all experts, v for own expert ----
        float ka0 = kvdb[0*64+c], ka1 = kvdb[1*64+c], ka2 = kvdb[2*64+c], ka3 = kvdb[3*64+c];
        float va = kvdb[ep * 64 + 32 + c];
#pragma unroll
        for (int dy = 0; dy < 7; ++dy) {
            const unsigned long long E = ehP[ly + dy];
            const int rk = (ly + dy) * 15 + lx;
#pragma unroll
            for (int dx = 0; dx < 7; ++dx) {
                int code = (int)((E >> ((lx + dx) * 4)) & 15ull);
                if (code) {
                    int ie = code - 1;
                    float2 w2 = wkvS[ie * 49 + dy * 7 + dx];
                    float wv = w2.x * khS[rk + dx];
                    ka0 += (ie == 0) ? wv : 0.f;
                    ka1 += (ie == 1) ? wv : 0.f;
                    ka2 += (ie == 2) ? wv : 0.f;
                    ka3 += (ie == 3) ? wv : 0.f;
                    if (ie == ep) va += w2.y * vhS[rk + dx];
                }
            }
        }
        kAS[0*64+t] = ka0; kAS[1*64+t] = ka1; kAS[2*64+t] = ka2; kAS[3*64+t] = ka3;
        vOwn[t * 33 + c] = va;
        __syncthreads();

        // ---- 8x8 circular convolution, own expert ----
        // q reads: uniform (sy,sx) -> 4-address broadcast, stride 65 -> distinct banks.
        // k reads: per-lane offset bijective over 64 -> exact 2 lanes/bank (free).
        const float* qrow = &qAS[ep * 65];
        const float* krow = &kAS[ep * 64];
        float oc = 0.f;
#pragma unroll
        for (int sy = 0; sy < 8; ++sy) {
            int ky = ((ly - sy) & 7) * 8;
#pragma unroll
            for (int sx = 0; sx < 8; ++sx)
                oc += qrow[sy * 8 + sx] * krow[ky + ((lx - sx) & 7)];
        }
        oOwn[t * 33 + c] = oc;
        __syncthreads();
    }

    // ---- epilogue, parallel over cq ----
    float* svS   = pool;        // [pix][65]
    float* uS    = oOwn;        // [pix][33] (oOwn dead after o_ regs loaded)
    float* combS = pool;        // [pix][65] (aliases svS after it is dead)

    for (int j = tid; j < 64 * 64; j += 256) {
        int c = j >> 6, pix = j & 63;
        int phw = (y0 + (pix >> 3)) * WW + x0 + (pix & 7);
        svS[pix * 65 + c] = shr[((size_t)(b * 64 + c)) * HWs + phw];
    }

    float o_[RK], vv_[RK];
#pragma unroll
    for (int c = 0; c < RK; ++c) { o_[c] = oOwn[t * 33 + c]; vv_[c] = vOwn[t * 33 + c]; }
    float mu = 0.f;
#pragma unroll
    for (int c = 0; c < RK; ++c) mu += o_[c];
    mu *= (1.0f / RK);
    float var = 0.f;
#pragma unroll
    for (int c = 0; c < RK; ++c) { float d = o_[c] - mu; var += d * d; }
    var *= (1.0f / RK);
    float inv = 1.0f / sqrtf(var + 1e-5f);
    float ttv[RK];
#pragma unroll
    for (int c = 0; c < RK; ++c)
        ttv[c] = ((o_[c] - mu) * inv * lnw[ep * RK + c] + lnb[ep * RK + c]) * vv_[c];

    const float g = gVal[base + hw];
    __syncthreads();   // svS ready, oOwn/vOwn reads done

    // u rows r = cq*8 .. cq*8+7
    for (int r8 = 0; r8 < 8; ++r8) {
        int r = cq * 8 + r8;
        const float* wp1 = &p1w[(size_t)(ep * RK + r) * DIMc];
        float z = 0.f;
#pragma unroll
        for (int c = 0; c < DIMc; ++c) z += wp1[c] * svS[t * 65 + c];
        z *= g;
        float gate = z / (1.f + expf(-z));
        float bdy = fpb[ep * RK + r] + dot32(&fpw[(size_t)(ep * RK + r) * RK], ttv);
        uS[t * 33 + r] = bdy * gate;
    }
    __syncthreads();   // uS ready, svS dead

    // comb channels oo = cq*16 .. +15
    for (int o16 = 0; o16 < 16; ++o16) {
        int oo = cq * 16 + o16;
        const float* wp2 = &p2w[(size_t)(ep * DIMc + oo) * RK];
        float a = 0.f;
#pragma unroll
        for (int r = 0; r < RK; ++r) a += wp2[r] * uS[t * 33 + r];
        float xv = x[((size_t)(b * DIMc + oo)) * HWs + hw];
        combS[t * 65 + oo] = g * a + g * g * xv;
    }
    __syncthreads();   // combS ready

    for (int o16 = 0; o16 < 16; ++o16) {
        int oo = cq * 16 + o16;
        const float* wo = &outw[oo * DIMc];
        float a = outb[oo];
#pragma unroll
        for (int c = 0; c < DIMc; ++c) a += wo[c] * combS[t * 65 + c];
        out[((size_t)(b * DIMc + oo)) * HWs + hw] = a;
    }
}

extern "C" void kernel_launch(void* const* d_in, const int* in_sizes, int n_in,
                              void* d_out, int out_size, void* d_ws, size_t ws_size,
                              hipStream_t stream) {
    const float* x    = (const float*)d_in[0];
    const float* shr  = (const float*)d_in[1];
    const float* rw   = (const float*)d_in[2];
    const float* rb_  = (const float*)d_in[3];
    const float* p0w  = (const float*)d_in[4];
    const float* p1w  = (const float*)d_in[5];
    const float* p2w  = (const float*)d_in[6];
    const float* qw   = (const float*)d_in[7];
    const float* qdw  = (const float*)d_in[8];
    const float* qdb  = (const float*)d_in[9];
    const float* kvw  = (const float*)d_in[10];
    const float* kvdw = (const float*)d_in[11];
    const float* kvdb = (const float*)d_in[12];
    const float* lnw  = (const float*)d_in[13];
    const float* lnb  = (const float*)d_in[14];
    const float* fpw  = (const float*)d_in[15];
    const float* fpb  = (const float*)d_in[16];
    const float* outw = (const float*)d_in[17];
    const float* outb = (const float*)d_in[18];
    float* out = (float*)d_out;

    const int N = 4 * HWs;
    char* ws = (char*)d_ws;
    int*   eIdx  = (int*)ws;            ws += (size_t)N * sizeof(int);
    float* gV    = (float*)ws;          ws += (size_t)N * sizeof(float);
    float* qpre  = (float*)ws;          ws += (size_t)N * RK * sizeof(float);
    float* kvpre = (float*)ws;          ws += (size_t)N * 2 * RK * sizeof(float);

    k_router<<<N / 256, 256, 0, stream>>>(x, rw, rb_, p0w, qw, kvw, eIdx, gV, qpre, kvpre);
    k_patch<<<4 * 32 * 32, 256, 0, stream>>>(x, shr, eIdx, gV, qpre, kvpre,
                                             p1w, qdw, qdb, kvdw, kvdb,
                                             lnw, lnb, fpw, fpb, p2w, outw, outb, out);
}

// Round 3
// 1599.918 us; speedup vs baseline: 1.3311x; 1.0868x over previous
//
#include <hip/hip_runtime.h>
#include <math.h>

#define HH 256
#define WW 256
#define HWs 65536
#define DIMc 64
#define RK 32

__device__ inline float dot64(const float* __restrict__ w, const float* v) {
    const float4* w4 = (const float4*)w;
    float a = 0.f;
#pragma unroll
    for (int i = 0; i < 16; ++i) {
        float4 ww = w4[i];
        a += ww.x * v[4*i] + ww.y * v[4*i+1] + ww.z * v[4*i+2] + ww.w * v[4*i+3];
    }
    return a;
}
__device__ inline float dot32(const float* __restrict__ w, const float* v) {
    const float4* w4 = (const float4*)w;
    float a = 0.f;
#pragma unroll
    for (int i = 0; i < 8; ++i) {
        float4 ww = w4[i];
        a += ww.x * v[4*i] + ww.y * v[4*i+1] + ww.z * v[4*i+2] + ww.w * v[4*i+3];
    }
    return a;
}

// K1: per-pixel router + pointwise preprojections, expert weights staged in LDS.
__global__ __launch_bounds__(256) void k_router(
    const float* __restrict__ x,
    const float* __restrict__ rw, const float* __restrict__ rb,
    const float* __restrict__ p0w, const float* __restrict__ qw, const float* __restrict__ kvw,
    int* __restrict__ eIdx, float* __restrict__ gVal,
    float* __restrict__ qpre, float* __restrict__ kvpre)
{
    __shared__ float wl[12544];
    const int tid = threadIdx.x;
    const int p = blockIdx.x * 256 + tid;   // [0, B*HW)
    const int b = p >> 16;
    const int hw = p & 0xFFFF;

    for (int i = tid; i < 256;  i += 256) wl[i] = rw[i];
    for (int i = tid; i < 8192; i += 256) wl[256 + i] = p0w[i];
    for (int i = tid; i < 4096; i += 256) wl[8448 + i] = qw[i];
    __syncthreads();

    const float* xb = x + ((size_t)b * DIMc) * HWs + hw;
    float xr[DIMc];
#pragma unroll
    for (int c = 0; c < DIMc; ++c) xr[c] = xb[(size_t)c * HWs];

    float l[4];
#pragma unroll
    for (int e = 0; e < 4; ++e) l[e] = rb[e] + dot64(&wl[e * DIMc], xr);

    float m = fmaxf(fmaxf(l[0], l[1]), fmaxf(l[2], l[3]));
    int e = (l[0] == m) ? 0 : (l[1] == m) ? 1 : (l[2] == m) ? 2 : 3;
    float s = expf(l[0]-m) + expf(l[1]-m) + expf(l[2]-m) + expf(l[3]-m);
    float g = 1.0f / s;
    eIdx[p] = e;
    gVal[p] = g;

    float h1[RK];
    const float* w0 = &wl[256 + e * RK * DIMc];
#pragma unroll
    for (int r = 0; r < RK; ++r) h1[r] = g * dot64(&w0[r * DIMc], xr);

    const float* wq = &wl[8448 + e * RK * RK];
#pragma unroll
    for (int r = 0; r < RK; ++r)
        qpre[((size_t)(b * RK + r)) * HWs + hw] = dot32(&wq[r * RK], h1);

    __syncthreads();
    for (int i = tid; i < 8192; i += 256) wl[i] = kvw[i];
    __syncthreads();

    const float* wk = &wl[e * 2 * RK * RK];
#pragma unroll
    for (int r = 0; r < 2 * RK; ++r)
        kvpre[((size_t)(b * 2 * RK + r)) * HWs + hw] = dot32(&wk[r * RK], h1);
}

// K2: one 256-thread block per 8x8 patch; 4 channels in flight (cq = tid>>6).
// LDS total 40432 B -> LDS_Block_Size 40448 -> 4 blocks/CU.
// VGPR: plain __launch_bounds__(256); epilogue keeps ONE 32-float array live
// (ttv computed in place over o_) so natural allocation stays <= 128
// (the 64-VGPR forced bucket of round 2 caused 2.5 GB of scratch traffic).
// pool[5856] floats, main-loop layout per cq:
//   kh   @0    : 4 x 210 (14x14, stride 15)
//   vh   @840  : 4 x 210
//   qh   @1680 : 4 x 100 (10x10, stride 10)
//   qA   @2080 : 4 x [4 experts x 65]  (stride 65: expert bank offset +1, kills 4-way q conflict)
//   kA   @3120 : 4 x [4 experts x 64]  (stride 64: offsets alone give exact 2 lanes/bank = free)
//   wq3  @4144 : 4 x 36
//   wkv7 @4288 : 4 x 196 float2 (.x=wk, .y=wv; ie-broadcast reads are conflict-free)
// epilogue aliases: svS/combS = pool [pix][65]; uS = oOwn (dead by then).
// ehP[14] u64: 4-bit code per halo cell (expert+1, 0=outside), b64 broadcast per dy row.
__global__ __launch_bounds__(256) void k_patch(
    const float* __restrict__ x, const float* __restrict__ shr,
    const int* __restrict__ eIdx, const float* __restrict__ gVal,
    const float* __restrict__ qpre, const float* __restrict__ kvpre,
    const float* __restrict__ p1w,
    const float* __restrict__ qdw, const float* __restrict__ qdb,
    const float* __restrict__ kvdw, const float* __restrict__ kvdb,
    const float* __restrict__ lnw, const float* __restrict__ lnb,
    const float* __restrict__ fpw, const float* __restrict__ fpb,
    const float* __restrict__ p2w,
    const float* __restrict__ outw, const float* __restrict__ outb,
    float* __restrict__ out)
{
    __shared__ __align__(16) float pool[5856];
    __shared__ float oOwn[64 * 33];
    __shared__ float vOwn[64 * 33];
    __shared__ unsigned long long ehP[14];

    const int tid = threadIdx.x;
    const int cq = tid >> 6;
    const int t  = tid & 63;
    const int bid = blockIdx.x;
    const int b  = bid >> 10;
    const int pp = bid & 1023;
    const int py = pp >> 5, px = pp & 31;
    const int y0 = py * 8, x0 = px * 8;
    const int ly = t >> 3, lx = t & 7;
    const int gy = y0 + ly, gx = x0 + lx;
    const int hw = gy * WW + gx;
    const size_t base = (size_t)b * HWs;

    // ---- build packed expert halo ----
    unsigned int* ehW = (unsigned int*)ehP;
    if (tid < 28) ehW[tid] = 0u;
    __syncthreads();
    for (int j = tid; j < 196; j += 256) {
        int r = j / 14, cc = j % 14;
        int yy = y0 - 3 + r, xx = x0 - 3 + cc;
        if ((unsigned)yy < HH && (unsigned)xx < WW) {
            unsigned int code = (unsigned)eIdx[base + yy * WW + xx] + 1u;
            atomicOr(&ehW[r * 2 + (cc >> 3)], code << ((cc & 7) * 4));
        }
    }
    __syncthreads();
    const int ep = (int)((ehP[ly + 3] >> ((lx + 3) * 4)) & 15ull) - 1;

    float*  khS  = pool + cq * 210;
    float*  vhS  = pool + 840 + cq * 210;
    float*  qhS  = pool + 1680 + cq * 100;
    float*  qAS  = pool + 2080 + cq * 260;
    float*  kAS  = pool + 3120 + cq * 256;
    float*  wq3S = pool + 4144 + cq * 36;
    float2* wkvS = (float2*)(pool + 4288) + cq * 196;

    for (int ch = 0; ch < 8; ++ch) {
        const int c = ch * 4 + cq;
        // ---- stage planes + weights for this channel ----
        for (int j = t; j < 196; j += 64) {
            int r = j / 14, cc = j % 14;
            int yy = y0 - 3 + r, xx = x0 - 3 + cc;
            float kv_ = 0.f, vv_ = 0.f;
            if ((unsigned)yy < HH && (unsigned)xx < WW) {
                size_t o1 = ((size_t)(b * 64 + c)) * HWs + yy * WW + xx;
                kv_ = kvpre[o1];
                vv_ = kvpre[o1 + (size_t)32 * HWs];
            }
            khS[r * 15 + cc] = kv_;
            vhS[r * 15 + cc] = vv_;
        }
        for (int j = t; j < 100; j += 64) {
            int r = j / 10, cc = j % 10;
            int yy = y0 - 1 + r, xx = x0 - 1 + cc;
            float qv = 0.f;
            if ((unsigned)yy < HH && (unsigned)xx < WW)
                qv = qpre[((size_t)(b * RK + c)) * HWs + yy * WW + xx];
            qhS[r * 10 + cc] = qv;
        }
        if (t < 36) wq3S[t] = qdw[(t / 9) * RK * 9 + c * 9 + (t % 9)];
        for (int j = t; j < 196; j += 64) {
            int i = j / 49, kk2 = j % 49;
            wkvS[j] = make_float2(kvdw[((size_t)(i * 64 + c)) * 49 + kk2],
                                  kvdw[((size_t)(i * 64 + 32 + c)) * 49 + kk2]);
        }
        __syncthreads();

        // ---- dw3: q for all experts at this pixel (code col offset +2, row offset +2) ----
        float qa0 = qdb[0*RK+c], qa1 = qdb[1*RK+c], qa2 = qdb[2*RK+c], qa3 = qdb[3*RK+c];
#pragma unroll
        for (int dy = 0; dy < 3; ++dy) {
            const unsigned long long E = ehP[ly + dy + 2];
            const int rq = (ly + dy) * 10 + lx;
#pragma unroll
            for (int dx = 0; dx < 3; ++dx) {
                int code = (int)((E >> ((lx + dx + 2) * 4)) & 15ull);
                if (code) {
                    int ie = code - 1;
                    float wv = wq3S[ie * 9 + dy * 3 + dx] * qhS[rq + dx];
                    qa0 += (ie == 0) ? wv : 0.f;
                    qa1 += (ie == 1) ? wv : 0.f;
                    qa2 += (ie == 2) ? wv : 0.f;
                    qa3 += (ie == 3) ? wv : 0.f;
                }
            }
        }
        qAS[0*65+t] = qa0; qAS[1*65+t] = qa1; qAS[2*65+t] = qa2; qAS[3*65+t] = qa3;

        // ---- dw7: k for all experts, v for own expert ----
        float ka0 = kvdb[0*64+c], ka1 = kvdb[1*64+c], ka2 = kvdb[2*64+c], ka3 = kvdb[3*64+c];
        float va = kvdb[ep * 64 + 32 + c];
#pragma unroll
        for (int dy = 0; dy < 7; ++dy) {
            const unsigned long long E = ehP[ly + dy];
            const int rk = (ly + dy) * 15 + lx;
#pragma unroll
            for (int dx = 0; dx < 7; ++dx) {
                int code = (int)((E >> ((lx + dx) * 4)) & 15ull);
                if (code) {
                    int ie = code - 1;
                    float2 w2 = wkvS[ie * 49 + dy * 7 + dx];
                    float wv = w2.x * khS[rk + dx];
                    ka0 += (ie == 0) ? wv : 0.f;
                    ka1 += (ie == 1) ? wv : 0.f;
                    ka2 += (ie == 2) ? wv : 0.f;
                    ka3 += (ie == 3) ? wv : 0.f;
                    if (ie == ep) va += w2.y * vhS[rk + dx];
                }
            }
        }
        kAS[0*64+t] = ka0; kAS[1*64+t] = ka1; kAS[2*64+t] = ka2; kAS[3*64+t] = ka3;
        vOwn[t * 33 + c] = va;
        __syncthreads();

        // ---- 8x8 circular convolution, own expert ----
        // q reads: uniform (sy,sx) -> 4-address broadcast, stride 65 -> distinct banks.
        // k reads: per-lane offset bijective over 64 -> exact 2 lanes/bank (free).
        const float* qrow = &qAS[ep * 65];
        const float* krow = &kAS[ep * 64];
        float oc = 0.f;
#pragma unroll
        for (int sy = 0; sy < 8; ++sy) {
            int ky = ((ly - sy) & 7) * 8;
#pragma unroll
            for (int sx = 0; sx < 8; ++sx)
                oc += qrow[sy * 8 + sx] * krow[ky + ((lx - sx) & 7)];
        }
        oOwn[t * 33 + c] = oc;
        __syncthreads();
    }

    // ---- epilogue, parallel over cq ----
    float* svS   = pool;        // [pix][65]
    float* uS    = oOwn;        // [pix][33] (oOwn dead after o_ regs loaded)
    float* combS = pool;        // [pix][65] (aliases svS after it is dead)

    for (int j = tid; j < 64 * 64; j += 256) {
        int c = j >> 6, pix = j & 63;
        int phw = (y0 + (pix >> 3)) * WW + x0 + (pix & 7);
        svS[pix * 65 + c] = shr[((size_t)(b * 64 + c)) * HWs + phw];
    }

    // one live 32-array: o_ -> (in place) -> ttv
    float o_[RK];
#pragma unroll
    for (int c = 0; c < RK; ++c) o_[c] = oOwn[t * 33 + c];
    float mu = 0.f;
#pragma unroll
    for (int c = 0; c < RK; ++c) mu += o_[c];
    mu *= (1.0f / RK);
    float var = 0.f;
#pragma unroll
    for (int c = 0; c < RK; ++c) { float d = o_[c] - mu; var += d * d; }
    var *= (1.0f / RK);
    float inv = 1.0f / sqrtf(var + 1e-5f);
#pragma unroll
    for (int c = 0; c < RK; ++c)
        o_[c] = ((o_[c] - mu) * inv * lnw[ep * RK + c] + lnb[ep * RK + c]) * vOwn[t * 33 + c];

    const float g = gVal[base + hw];
    __syncthreads();   // svS ready, oOwn/vOwn reads done

    // u rows r = cq*8 .. cq*8+7
    for (int r8 = 0; r8 < 8; ++r8) {
        int r = cq * 8 + r8;
        const float* wp1 = &p1w[(size_t)(ep * RK + r) * DIMc];
        float z = 0.f;
#pragma unroll
        for (int c = 0; c < DIMc; ++c) z += wp1[c] * svS[t * 65 + c];
        z *= g;
        float gate = z / (1.f + expf(-z));
        float bdy = fpb[ep * RK + r] + dot32(&fpw[(size_t)(ep * RK + r) * RK], o_);
        uS[t * 33 + r] = bdy * gate;
    }
    __syncthreads();   // uS ready, svS dead

    // comb channels oo = cq*16 .. +15
    for (int o16 = 0; o16 < 16; ++o16) {
        int oo = cq * 16 + o16;
        const float* wp2 = &p2w[(size_t)(ep * DIMc + oo) * RK];
        float a = 0.f;
#pragma unroll
        for (int r = 0; r < RK; ++r) a += wp2[r] * uS[t * 33 + r];
        float xv = x[((size_t)(b * DIMc + oo)) * HWs + hw];
        combS[t * 65 + oo] = g * a + g * g * xv;
    }
    __syncthreads();   // combS ready

    for (int o16 = 0; o16 < 16; ++o16) {
        int oo = cq * 16 + o16;
        const float* wo = &outw[oo * DIMc];
        float a = outb[oo];
#pragma unroll
        for (int c = 0; c < DIMc; ++c) a += wo[c] * combS[t * 65 + c];
        out[((size_t)(b * DIMc + oo)) * HWs + hw] = a;
    }
}

extern "C" void kernel_launch(void* const* d_in, const int* in_sizes, int n_in,
                              void* d_out, int out_size, void* d_ws, size_t ws_size,
                              hipStream_t stream) {
    const float* x    = (const float*)d_in[0];
    const float* shr  = (const float*)d_in[1];
    const float* rw   = (const float*)d_in[2];
    const float* rb_  = (const float*)d_in[3];
    const float* p0w  = (const float*)d_in[4];
    const float* p1w  = (const float*)d_in[5];
    const float* p2w  = (const float*)d_in[6];
    const float* qw   = (const float*)d_in[7];
    const float* qdw  = (const float*)d_in[8];
    const float* qdb  = (const float*)d_in[9];
    const float* kvw  = (const float*)d_in[10];
    const float* kvdw = (const float*)d_in[11];
    const float* kvdb = (const float*)d_in[12];
    const float* lnw  = (const float*)d_in[13];
    const float* lnb  = (const float*)d_in[14];
    const float* fpw  = (const float*)d_in[15];
    const float* fpb  = (const float*)d_in[16];
    const float* outw = (const float*)d_in[17];
    const float* outb = (const float*)d_in[18];
    float* out = (float*)d_out;

    const int N = 4 * HWs;
    char* ws = (char*)d_ws;
    int*   eIdx  = (int*)ws;            ws += (size_t)N * sizeof(int);
    float* gV    = (float*)ws;          ws += (size_t)N * sizeof(float);
    float* qpre  = (float*)ws;          ws += (size_t)N * RK * sizeof(float);
    float* kvpre = (float*)ws;          ws += (size_t)N * 2 * RK * sizeof(float);

    k_router<<<N / 256, 256, 0, stream>>>(x, rw, rb_, p0w, qw, kvw, eIdx, gV, qpre, kvpre);
    k_patch<<<4 * 32 * 32, 256, 0, stream>>>(x, shr, eIdx, gV, qpre, kvpre,
                                             p1w, qdw, qdb, kvdw, kvdb,
                                             lnw, lnb, fpw, fpb, p2w, outw, outb, out);
}

// Round 4
// 1214.346 us; speedup vs baseline: 1.7538x; 1.3175x over previous
//
#include <hip/hip_runtime.h>
#include <math.h>

#define HH 256
#define WW 256
#define HWs 65536
#define DIMc 64
#define RK 32

__device__ inline float dot64(const float* __restrict__ w, const float* v) {
    const float4* w4 = (const float4*)w;
    float a = 0.f;
#pragma unroll
    for (int i = 0; i < 16; ++i) {
        float4 ww = w4[i];
        a += ww.x * v[4*i] + ww.y * v[4*i+1] + ww.z * v[4*i+2] + ww.w * v[4*i+3];
    }
    return a;
}
__device__ inline float dot32(const float* __restrict__ w, const float* v) {
    const float4* w4 = (const float4*)w;
    float a = 0.f;
#pragma unroll
    for (int i = 0; i < 8; ++i) {
        float4 ww = w4[i];
        a += ww.x * v[4*i] + ww.y * v[4*i+1] + ww.z * v[4*i+2] + ww.w * v[4*i+3];
    }
    return a;
}

// K1: per-pixel router + pointwise preprojections, expert weights staged in LDS.
__global__ __launch_bounds__(256) void k_router(
    const float* __restrict__ x,
    const float* __restrict__ rw, const float* __restrict__ rb,
    const float* __restrict__ p0w, const float* __restrict__ qw, const float* __restrict__ kvw,
    int* __restrict__ eIdx, float* __restrict__ gVal,
    float* __restrict__ qpre, float* __restrict__ kvpre)
{
    __shared__ float wl[12544];
    const int tid = threadIdx.x;
    const int p = blockIdx.x * 256 + tid;   // [0, B*HW)
    const int b = p >> 16;
    const int hw = p & 0xFFFF;

    for (int i = tid; i < 256;  i += 256) wl[i] = rw[i];
    for (int i = tid; i < 8192; i += 256) wl[256 + i] = p0w[i];
    for (int i = tid; i < 4096; i += 256) wl[8448 + i] = qw[i];
    __syncthreads();

    const float* xb = x + ((size_t)b * DIMc) * HWs + hw;
    float xr[DIMc];
#pragma unroll
    for (int c = 0; c < DIMc; ++c) xr[c] = xb[(size_t)c * HWs];

    float l[4];
#pragma unroll
    for (int e = 0; e < 4; ++e) l[e] = rb[e] + dot64(&wl[e * DIMc], xr);

    float m = fmaxf(fmaxf(l[0], l[1]), fmaxf(l[2], l[3]));
    int e = (l[0] == m) ? 0 : (l[1] == m) ? 1 : (l[2] == m) ? 2 : 3;
    float s = expf(l[0]-m) + expf(l[1]-m) + expf(l[2]-m) + expf(l[3]-m);
    float g = 1.0f / s;
    eIdx[p] = e;
    gVal[p] = g;

    float h1[RK];
    const float* w0 = &wl[256 + e * RK * DIMc];
#pragma unroll
    for (int r = 0; r < RK; ++r) h1[r] = g * dot64(&w0[r * DIMc], xr);

    const float* wq = &wl[8448 + e * RK * RK];
#pragma unroll
    for (int r = 0; r < RK; ++r)
        qpre[((size_t)(b * RK + r)) * HWs + hw] = dot32(&wq[r * RK], h1);

    __syncthreads();
    for (int i = tid; i < 8192; i += 256) wl[i] = kvw[i];
    __syncthreads();

    const float* wk = &wl[e * 2 * RK * RK];
#pragma unroll
    for (int r = 0; r < 2 * RK; ++r)
        kvpre[((size_t)(b * 2 * RK + r)) * HWs + hw] = dot32(&wk[r * RK], h1);
}

// W2[e][r][o] = sum_c outw[o][c] * p2w[e][c][r]   (8192 elems, tiny)
__global__ void k_w2(const float* __restrict__ outw, const float* __restrict__ p2w,
                     float* __restrict__ W2)
{
    int j = blockIdx.x * 256 + threadIdx.x;
    if (j >= 8192) return;
    int e = j >> 11, r = (j & 2047) >> 6, o = j & 63;
    float s = 0.f;
    for (int c = 0; c < DIMc; ++c)
        s += outw[o * 64 + c] * p2w[(size_t)(e * 64 + c) * 32 + r];
    W2[j] = s;
}

// K2: main loop ONLY (dw convs + circular conv). One 256-thread block per 8x8
// patch; 4 channels in flight (cq = tid>>6). Epilogue moved to k_epiA/k_epiB,
// which removes the o_[32] register pipeline (R2 proved it spills under a VGPR
// cap) and the oOwn/vOwn/svS LDS arrays.
// LDS = pool 23424 B + ehP 112 B ~= 23.5 KB -> 6-block LDS cap; VGPR target <=96.
// o and v planes are written into d_out (o at b*64+c, v at b*64+32+c); k_epiB
// later overwrites all of d_out with the final result.
__global__ __launch_bounds__(256) void k_patch(
    const int* __restrict__ eIdx,
    const float* __restrict__ qpre, const float* __restrict__ kvpre,
    const float* __restrict__ qdw, const float* __restrict__ qdb,
    const float* __restrict__ kvdw, const float* __restrict__ kvdb,
    float* __restrict__ ovB)
{
    __shared__ __align__(16) float pool[5856];
    __shared__ unsigned long long ehP[14];

    const int tid = threadIdx.x;
    const int cq = tid >> 6;
    const int t  = tid & 63;
    const int bid = blockIdx.x;
    const int b  = bid >> 10;
    const int pp = bid & 1023;
    const int py = pp >> 5, px = pp & 31;
    const int y0 = py * 8, x0 = px * 8;
    const int ly = t >> 3, lx = t & 7;
    const int gy = y0 + ly, gx = x0 + lx;
    const int hw = gy * WW + gx;
    const size_t base = (size_t)b * HWs;

    // ---- build packed expert halo: 4-bit code (expert+1, 0=outside) ----
    unsigned int* ehW = (unsigned int*)ehP;
    if (tid < 28) ehW[tid] = 0u;
    __syncthreads();
    for (int j = tid; j < 196; j += 256) {
        int r = j / 14, cc = j % 14;
        int yy = y0 - 3 + r, xx = x0 - 3 + cc;
        if ((unsigned)yy < HH && (unsigned)xx < WW) {
            unsigned int code = (unsigned)eIdx[base + yy * WW + xx] + 1u;
            atomicOr(&ehW[r * 2 + (cc >> 3)], code << ((cc & 7) * 4));
        }
    }
    __syncthreads();
    const int ep = (int)((ehP[ly + 3] >> ((lx + 3) * 4)) & 15ull) - 1;

    float*  khS  = pool + cq * 210;
    float*  vhS  = pool + 840 + cq * 210;
    float*  qhS  = pool + 1680 + cq * 100;
    float*  qAS  = pool + 2080 + cq * 260;   // stride 65 per expert
    float*  kAS  = pool + 3120 + cq * 256;   // stride 64 per expert (2 lanes/bank = free)
    float*  wq3S = pool + 4144 + cq * 36;
    float2* wkvS = (float2*)(pool + 4288) + cq * 196;

    for (int ch = 0; ch < 8; ++ch) {
        const int c = ch * 4 + cq;
        // ---- stage planes + weights for this channel ----
        for (int j = t; j < 196; j += 64) {
            int r = j / 14, cc = j % 14;
            int yy = y0 - 3 + r, xx = x0 - 3 + cc;
            float kv_ = 0.f, vv_ = 0.f;
            if ((unsigned)yy < HH && (unsigned)xx < WW) {
                size_t o1 = ((size_t)(b * 64 + c)) * HWs + yy * WW + xx;
                kv_ = kvpre[o1];
                vv_ = kvpre[o1 + (size_t)32 * HWs];
            }
            khS[r * 15 + cc] = kv_;
            vhS[r * 15 + cc] = vv_;
        }
        for (int j = t; j < 100; j += 64) {
            int r = j / 10, cc = j % 10;
            int yy = y0 - 1 + r, xx = x0 - 1 + cc;
            float qv = 0.f;
            if ((unsigned)yy < HH && (unsigned)xx < WW)
                qv = qpre[((size_t)(b * RK + c)) * HWs + yy * WW + xx];
            qhS[r * 10 + cc] = qv;
        }
        if (t < 36) wq3S[t] = qdw[(t / 9) * RK * 9 + c * 9 + (t % 9)];
        for (int j = t; j < 196; j += 64) {
            int i = j / 49, kk2 = j % 49;
            wkvS[j] = make_float2(kvdw[((size_t)(i * 64 + c)) * 49 + kk2],
                                  kvdw[((size_t)(i * 64 + 32 + c)) * 49 + kk2]);
        }
        __syncthreads();

        // ---- dw3: q for all experts at this pixel ----
        float qa0 = qdb[0*RK+c], qa1 = qdb[1*RK+c], qa2 = qdb[2*RK+c], qa3 = qdb[3*RK+c];
#pragma unroll
        for (int dy = 0; dy < 3; ++dy) {
            const unsigned long long E = ehP[ly + dy + 2];
            const int rq = (ly + dy) * 10 + lx;
#pragma unroll
            for (int dx = 0; dx < 3; ++dx) {
                int code = (int)((E >> ((lx + dx + 2) * 4)) & 15ull);
                if (code) {
                    int ie = code - 1;
                    float wv = wq3S[ie * 9 + dy * 3 + dx] * qhS[rq + dx];
                    qa0 += (ie == 0) ? wv : 0.f;
                    qa1 += (ie == 1) ? wv : 0.f;
                    qa2 += (ie == 2) ? wv : 0.f;
                    qa3 += (ie == 3) ? wv : 0.f;
                }
            }
        }
        qAS[0*65+t] = qa0; qAS[1*65+t] = qa1; qAS[2*65+t] = qa2; qAS[3*65+t] = qa3;

        // ---- dw7: k for all experts, v for own expert ----
        float ka0 = kvdb[0*64+c], ka1 = kvdb[1*64+c], ka2 = kvdb[2*64+c], ka3 = kvdb[3*64+c];
        float va = kvdb[ep * 64 + 32 + c];
#pragma unroll
        for (int dy = 0; dy < 7; ++dy) {
            const unsigned long long E = ehP[ly + dy];
            const int rk = (ly + dy) * 15 + lx;
#pragma unroll
            for (int dx = 0; dx < 7; ++dx) {
                int code = (int)((E >> ((lx + dx) * 4)) & 15ull);
                if (code) {
                    int ie = code - 1;
                    float2 w2 = wkvS[ie * 49 + dy * 7 + dx];
                    float wv = w2.x * khS[rk + dx];
                    ka0 += (ie == 0) ? wv : 0.f;
                    ka1 += (ie == 1) ? wv : 0.f;
                    ka2 += (ie == 2) ? wv : 0.f;
                    ka3 += (ie == 3) ? wv : 0.f;
                    if (ie == ep) va += w2.y * vhS[rk + dx];
                }
            }
        }
        kAS[0*64+t] = ka0; kAS[1*64+t] = ka1; kAS[2*64+t] = ka2; kAS[3*64+t] = ka3;
        ovB[((size_t)(b * 64 + 32 + c)) * HWs + hw] = va;   // v plane
        __syncthreads();

        // ---- 8x8 circular convolution, own expert ----
        const float* qrow = &qAS[ep * 65];
        const float* krow = &kAS[ep * 64];
        float oc = 0.f;
#pragma unroll
        for (int sy = 0; sy < 8; ++sy) {
            int ky = ((ly - sy) & 7) * 8;
#pragma unroll
            for (int sx = 0; sx < 8; ++sx)
                oc += qrow[sy * 8 + sx] * krow[ky + ((lx - sx) & 7)];
        }
        ovB[((size_t)(b * 64 + c)) * HWs + hw] = oc;        // o plane
        // no trailing barrier: next staging writes kh/vh/qh/wq3/wkv7 only, and
        // the post-staging barrier orders those vs this circconv's qA/kA reads.
    }
}

// K3a: per-pixel LN(o)*v -> ttv; z = p1w.shared; u = silu(g z) * (fpw.ttv + fpb).
// Expert weight arrays in LDS with +1 expert-stride padding (2049/1025/33) so
// the 4-way expert-divergent broadcast hits 4 distinct banks (conflict-free).
__global__ __launch_bounds__(256) void k_epiA(
    const float* __restrict__ ovB, const float* __restrict__ shr,
    const int* __restrict__ eIdx, const float* __restrict__ gVal,
    const float* __restrict__ p1w,
    const float* __restrict__ lnw, const float* __restrict__ lnb,
    const float* __restrict__ fpw, const float* __restrict__ fpb,
    float* __restrict__ uPl)
{
    __shared__ float p1wS[4 * 2049];
    __shared__ float fpwS[4 * 1025];
    __shared__ float lnwS[132], lnbS[132], fpbS[132];
    const int tid = threadIdx.x;
    for (int i = tid; i < 8192; i += 256) p1wS[(i >> 11) * 2049 + (i & 2047)] = p1w[i];
    for (int i = tid; i < 4096; i += 256) fpwS[(i >> 10) * 1025 + (i & 1023)] = fpw[i];
    if (tid < 128) {
        lnwS[(tid >> 5) * 33 + (tid & 31)] = lnw[tid];
        lnbS[(tid >> 5) * 33 + (tid & 31)] = lnb[tid];
        fpbS[(tid >> 5) * 33 + (tid & 31)] = fpb[tid];
    }
    __syncthreads();

    const int p = blockIdx.x * 256 + tid;
    const int b = p >> 16;
    const int hw = p & 0xFFFF;
    const int ep = eIdx[p];
    const float g = gVal[p];

    float o[RK];
#pragma unroll
    for (int c = 0; c < RK; ++c) o[c] = ovB[((size_t)(b * 64 + c)) * HWs + hw];
    float mu = 0.f;
#pragma unroll
    for (int c = 0; c < RK; ++c) mu += o[c];
    mu *= (1.0f / RK);
    float var = 0.f;
#pragma unroll
    for (int c = 0; c < RK; ++c) { float d = o[c] - mu; var += d * d; }
    var *= (1.0f / RK);
    float inv = 1.0f / sqrtf(var + 1e-5f);
#pragma unroll
    for (int c = 0; c < RK; ++c)
        o[c] = ((o[c] - mu) * inv * lnwS[ep * 33 + c] + lnbS[ep * 33 + c])
               * ovB[((size_t)(b * 64 + 32 + c)) * HWs + hw];

    float z[RK];
#pragma unroll
    for (int r = 0; r < RK; ++r) z[r] = 0.f;
    for (int c = 0; c < DIMc; ++c) {
        float shc = shr[((size_t)(b * 64 + c)) * HWs + hw];
        const float* w = &p1wS[ep * 2049 + c];   // stride 64 over r; bank (ep+c)%32
#pragma unroll
        for (int r = 0; r < RK; ++r) z[r] += w[r * 64] * shc;
    }

#pragma unroll
    for (int r = 0; r < RK; ++r) {
        float zz = z[r] * g;
        float gate = zz / (1.f + expf(-zz));
        const float* w = &fpwS[ep * 1025 + r * 32];
        float s = fpbS[ep * 33 + r];
#pragma unroll
        for (int c = 0; c < RK; ++c) s += w[c] * o[c];
        uPl[((size_t)(b * RK + r)) * HWs + hw] = s * gate;
    }
}

// K3b: out = outb + g^2*(outw.x) + g*(W2[ep].u)  -- comb/outw folded via W2.
__global__ __launch_bounds__(256) void k_epiB(
    const float* __restrict__ x, const float* __restrict__ uPl,
    const int* __restrict__ eIdx, const float* __restrict__ gVal,
    const float* __restrict__ W2, const float* __restrict__ outw,
    const float* __restrict__ outb,
    float* __restrict__ out)
{
    __shared__ float owT[64 * 65];     // [c][o], stride 65
    __shared__ float w2S[4 * 2049];    // [e][r*64+o], expert stride 2049
    __shared__ float obS[64];
    const int tid = threadIdx.x;
    for (int i = tid; i < 4096; i += 256) owT[(i & 63) * 65 + (i >> 6)] = outw[i];
    for (int i = tid; i < 8192; i += 256) w2S[(i >> 11) * 2049 + (i & 2047)] = W2[i];
    if (tid < 64) obS[tid] = outb[tid];
    __syncthreads();

    const int p = blockIdx.x * 256 + tid;
    const int b = p >> 16;
    const int hw = p & 0xFFFF;
    const int ep = eIdx[p];
    const float g = gVal[p];
    const float g2 = g * g;

    float acc[DIMc];
#pragma unroll
    for (int o = 0; o < DIMc; ++o) acc[o] = obS[o];

    for (int c = 0; c < DIMc; ++c) {
        float xc = g2 * x[((size_t)(b * 64 + c)) * HWs + hw];
        const float* w = &owT[c * 65];           // uniform addr -> broadcast
#pragma unroll
        for (int o = 0; o < DIMc; ++o) acc[o] += w[o] * xc;
    }
    for (int r = 0; r < RK; ++r) {
        float ur = g * uPl[((size_t)(b * RK + r)) * HWs + hw];
        const float* w = &w2S[ep * 2049 + r * 64];  // bank (ep+o)%32, 4 banks
#pragma unroll
        for (int o = 0; o < DIMc; ++o) acc[o] += w[o] * ur;
    }
#pragma unroll
    for (int o = 0; o < DIMc; ++o)
        out[((size_t)(b * 64 + o)) * HWs + hw] = acc[o];
}

extern "C" void kernel_launch(void* const* d_in, const int* in_sizes, int n_in,
                              void* d_out, int out_size, void* d_ws, size_t ws_size,
                              hipStream_t stream) {
    const float* x    = (const float*)d_in[0];
    const float* shr  = (const float*)d_in[1];
    const float* rw   = (const float*)d_in[2];
    const float* rb_  = (const float*)d_in[3];
    const float* p0w  = (const float*)d_in[4];
    const float* p1w  = (const float*)d_in[5];
    const float* p2w  = (const float*)d_in[6];
    const float* qw   = (const float*)d_in[7];
    const float* qdw  = (const float*)d_in[8];
    const float* qdb  = (const float*)d_in[9];
    const float* kvw  = (const float*)d_in[10];
    const float* kvdw = (const float*)d_in[11];
    const float* kvdb = (const float*)d_in[12];
    const float* lnw  = (const float*)d_in[13];
    const float* lnb  = (const float*)d_in[14];
    const float* fpw  = (const float*)d_in[15];
    const float* fpb  = (const float*)d_in[16];
    const float* outw = (const float*)d_in[17];
    const float* outb = (const float*)d_in[18];
    float* out = (float*)d_out;

    const int N = 4 * HWs;
    char* ws = (char*)d_ws;
    int*   eIdx  = (int*)ws;            ws += (size_t)N * sizeof(int);
    float* gV    = (float*)ws;          ws += (size_t)N * sizeof(float);
    float* qpre  = (float*)ws;          ws += (size_t)N * RK * sizeof(float);
    float* kvpre = (float*)ws;          ws += (size_t)N * 2 * RK * sizeof(float);
    float* W2    = (float*)ws;          ws += 8192 * sizeof(float);
    float* uPl   = qpre;   // qpre is dead after k_patch; reuse for u planes
    float* ovB   = out;    // o/v planes live in d_out until k_epiB overwrites it

    k_router<<<N / 256, 256, 0, stream>>>(x, rw, rb_, p0w, qw, kvw, eIdx, gV, qpre, kvpre);
    k_w2<<<32, 256, 0, stream>>>(outw, p2w, W2);
    k_patch<<<4 * 32 * 32, 256, 0, stream>>>(eIdx, qpre, kvpre,
                                             qdw, qdb, kvdw, kvdb, ovB);
    k_epiA<<<N / 256, 256, 0, stream>>>(ovB, shr, eIdx, gV, p1w, lnw, lnb, fpw, fpb, uPl);
    k_epiB<<<N / 256, 256, 0, stream>>>(x, uPl, eIdx, gV, W2, outw, outb, out);
}

// Round 5
// 816.466 us; speedup vs baseline: 2.6084x; 1.4873x over previous
//
#include <hip/hip_runtime.h>
#include <math.h>

#define HH 256
#define WW 256
#define HWs 65536
#define DIMc 64
#define RK 32

__device__ inline float dot64(const float* __restrict__ w, const float* v) {
    const float4* w4 = (const float4*)w;
    float a = 0.f;
#pragma unroll
    for (int i = 0; i < 16; ++i) {
        float4 ww = w4[i];
        a += ww.x * v[4*i] + ww.y * v[4*i+1] + ww.z * v[4*i+2] + ww.w * v[4*i+3];
    }
    return a;
}
__device__ inline float dot32(const float* __restrict__ w, const float* v) {
    const float4* w4 = (const float4*)w;
    float a = 0.f;
#pragma unroll
    for (int i = 0; i < 8; ++i) {
        float4 ww = w4[i];
        a += ww.x * v[4*i] + ww.y * v[4*i+1] + ww.z * v[4*i+2] + ww.w * v[4*i+3];
    }
    return a;
}

// K1: per-pixel router + pointwise preprojections.
// Expert weight strides padded (2048->2056, 1024->1032) so the 4 expert-
// divergent addresses of each b128 read hit 4 distinct bank groups
// (2056%32=8, 1032%32=8) instead of a 4-way same-bank conflict.
__global__ __launch_bounds__(256) void k_router(
    const float* __restrict__ x,
    const float* __restrict__ rw, const float* __restrict__ rb,
    const float* __restrict__ p0w, const float* __restrict__ qw, const float* __restrict__ kvw,
    int* __restrict__ eIdx, float* __restrict__ gVal,
    float* __restrict__ qpre, float* __restrict__ kvpre)
{
    // phase A: rw[256] @0, p0w @256 (stride 2056), qw @8480 (stride 1032)
    // phase B: kvw @0 (stride 2056)
    __shared__ __align__(16) float wl[12608];
    const int tid = threadIdx.x;
    const int p = blockIdx.x * 256 + tid;   // [0, B*HW)
    const int b = p >> 16;
    const int hw = p & 0xFFFF;

    for (int i = tid; i < 256;  i += 256) wl[i] = rw[i];
    for (int i = tid; i < 8192; i += 256) wl[256 + (i >> 11) * 2056 + (i & 2047)] = p0w[i];
    for (int i = tid; i < 4096; i += 256) wl[8480 + (i >> 10) * 1032 + (i & 1023)] = qw[i];
    __syncthreads();

    const float* xb = x + ((size_t)b * DIMc) * HWs + hw;
    float xr[DIMc];
#pragma unroll
    for (int c = 0; c < DIMc; ++c) xr[c] = xb[(size_t)c * HWs];

    float l[4];
#pragma unroll
    for (int e = 0; e < 4; ++e) l[e] = rb[e] + dot64(&wl[e * DIMc], xr);  // uniform addr -> broadcast

    float m = fmaxf(fmaxf(l[0], l[1]), fmaxf(l[2], l[3]));
    int e = (l[0] == m) ? 0 : (l[1] == m) ? 1 : (l[2] == m) ? 2 : 3;
    float s = expf(l[0]-m) + expf(l[1]-m) + expf(l[2]-m) + expf(l[3]-m);
    float g = 1.0f / s;
    eIdx[p] = e;
    gVal[p] = g;

    float h1[RK];
    const float* w0 = &wl[256 + e * 2056];
#pragma unroll
    for (int r = 0; r < RK; ++r) h1[r] = g * dot64(&w0[r * DIMc], xr);

    const float* wq = &wl[8480 + e * 1032];
#pragma unroll
    for (int r = 0; r < RK; ++r)
        qpre[((size_t)(b * RK + r)) * HWs + hw] = dot32(&wq[r * RK], h1);

    __syncthreads();
    for (int i = tid; i < 8192; i += 256) wl[(i >> 11) * 2056 + (i & 2047)] = kvw[i];
    __syncthreads();

    const float* wk = &wl[e * 2056];
#pragma unroll
    for (int r = 0; r < 2 * RK; ++r)
        kvpre[((size_t)(b * 2 * RK + r)) * HWs + hw] = dot32(&wk[r * RK], h1);
}

// W2[e][r][o] = sum_c outw[o][c] * p2w[e][c][r]   (8192 elems, tiny)
__global__ void k_w2(const float* __restrict__ outw, const float* __restrict__ p2w,
                     float* __restrict__ W2)
{
    int j = blockIdx.x * 256 + threadIdx.x;
    if (j >= 8192) return;
    int e = j >> 11, r = (j & 2047) >> 6, o = j & 63;
    float s = 0.f;
    for (int c = 0; c < DIMc; ++c)
        s += outw[o * 64 + c] * p2w[(size_t)(e * 64 + c) * 32 + r];
    W2[j] = s;
}

// K2: main loop only (dw convs + circular conv).
// __launch_bounds__(256,4): forces the 64-VGPR bucket (R2 evidence); the body
// is now small enough (natural 68) that this costs at most a couple of spill
// slots, and buys 33% -> ~46% occupancy.
// Halo plane strides chosen for exact 2-lanes/bank (free): kh/vh row stride 20
// (20*ly mod 32 = multiples of 4), qh row stride 12. qA stride 65, kA stride 64.
// pool[6496] floats (25984 B) + ehP -> ~26.1 KB LDS.
__global__ __launch_bounds__(256, 4) void k_patch(
    const int* __restrict__ eIdx,
    const float* __restrict__ qpre, const float* __restrict__ kvpre,
    const float* __restrict__ qdw, const float* __restrict__ qdb,
    const float* __restrict__ kvdw, const float* __restrict__ kvdb,
    float* __restrict__ ovB)
{
    __shared__ __align__(16) float pool[6496];
    __shared__ unsigned long long ehP[14];

    const int tid = threadIdx.x;
    const int cq = tid >> 6;
    const int t  = tid & 63;
    const int bid = blockIdx.x;
    const int b  = bid >> 10;
    const int pp = bid & 1023;
    const int py = pp >> 5, px = pp & 31;
    const int y0 = py * 8, x0 = px * 8;
    const int ly = t >> 3, lx = t & 7;
    const int gy = y0 + ly, gx = x0 + lx;
    const int hw = gy * WW + gx;
    const size_t base = (size_t)b * HWs;

    // ---- build packed expert halo: 4-bit code (expert+1, 0=outside) ----
    unsigned int* ehW = (unsigned int*)ehP;
    if (tid < 28) ehW[tid] = 0u;
    __syncthreads();
    for (int j = tid; j < 196; j += 256) {
        int r = j / 14, cc = j % 14;
        int yy = y0 - 3 + r, xx = x0 - 3 + cc;
        if ((unsigned)yy < HH && (unsigned)xx < WW) {
            unsigned int code = (unsigned)eIdx[base + yy * WW + xx] + 1u;
            atomicOr(&ehW[r * 2 + (cc >> 3)], code << ((cc & 7) * 4));
        }
    }
    __syncthreads();
    const int ep = (int)((ehP[ly + 3] >> ((lx + 3) * 4)) & 15ull) - 1;

    float*  khS  = pool + cq * 280;            // 14 rows, stride 20
    float*  vhS  = pool + 1120 + cq * 280;     // 14 rows, stride 20
    float*  qhS  = pool + 2240 + cq * 120;     // 10 rows, stride 12
    float*  qAS  = pool + 2720 + cq * 260;     // 4 experts, stride 65
    float*  kAS  = pool + 3760 + cq * 256;     // 4 experts, stride 64
    float*  wq3S = pool + 4784 + cq * 36;
    float2* wkvS = (float2*)(pool + 4928) + cq * 196;

    for (int ch = 0; ch < 8; ++ch) {
        const int c = ch * 4 + cq;
        // ---- stage planes + weights for this channel ----
        for (int j = t; j < 196; j += 64) {
            int r = j / 14, cc = j % 14;
            int yy = y0 - 3 + r, xx = x0 - 3 + cc;
            float kv_ = 0.f, vv_ = 0.f;
            if ((unsigned)yy < HH && (unsigned)xx < WW) {
                size_t o1 = ((size_t)(b * 64 + c)) * HWs + yy * WW + xx;
                kv_ = kvpre[o1];
                vv_ = kvpre[o1 + (size_t)32 * HWs];
            }
            khS[r * 20 + cc] = kv_;
            vhS[r * 20 + cc] = vv_;
        }
        for (int j = t; j < 100; j += 64) {
            int r = j / 10, cc = j % 10;
            int yy = y0 - 1 + r, xx = x0 - 1 + cc;
            float qv = 0.f;
            if ((unsigned)yy < HH && (unsigned)xx < WW)
                qv = qpre[((size_t)(b * RK + c)) * HWs + yy * WW + xx];
            qhS[r * 12 + cc] = qv;
        }
        if (t < 36) wq3S[t] = qdw[(t / 9) * RK * 9 + c * 9 + (t % 9)];
        for (int j = t; j < 196; j += 64) {
            int i = j / 49, kk2 = j % 49;
            wkvS[j] = make_float2(kvdw[((size_t)(i * 64 + c)) * 49 + kk2],
                                  kvdw[((size_t)(i * 64 + 32 + c)) * 49 + kk2]);
        }
        __syncthreads();

        // ---- dw3: q for all experts at this pixel ----
        float qa0 = qdb[0*RK+c], qa1 = qdb[1*RK+c], qa2 = qdb[2*RK+c], qa3 = qdb[3*RK+c];
#pragma unroll
        for (int dy = 0; dy < 3; ++dy) {
            const unsigned long long E = ehP[ly + dy + 2];
            const int rq = (ly + dy) * 12 + lx;
#pragma unroll
            for (int dx = 0; dx < 3; ++dx) {
                int code = (int)((E >> ((lx + dx + 2) * 4)) & 15ull);
                if (code) {
                    int ie = code - 1;
                    float wv = wq3S[ie * 9 + dy * 3 + dx] * qhS[rq + dx];
                    qa0 += (ie == 0) ? wv : 0.f;
                    qa1 += (ie == 1) ? wv : 0.f;
                    qa2 += (ie == 2) ? wv : 0.f;
                    qa3 += (ie == 3) ? wv : 0.f;
                }
            }
        }
        qAS[0*65+t] = qa0; qAS[1*65+t] = qa1; qAS[2*65+t] = qa2; qAS[3*65+t] = qa3;

        // ---- dw7: k for all experts, v for own expert ----
        float ka0 = kvdb[0*64+c], ka1 = kvdb[1*64+c], ka2 = kvdb[2*64+c], ka3 = kvdb[3*64+c];
        float va = kvdb[ep * 64 + 32 + c];
#pragma unroll
        for (int dy = 0; dy < 7; ++dy) {
            const unsigned long long E = ehP[ly + dy];
            const int rk = (ly + dy) * 20 + lx;
#pragma unroll
            for (int dx = 0; dx < 7; ++dx) {
                int code = (int)((E >> ((lx + dx) * 4)) & 15ull);
                if (code) {
                    int ie = code - 1;
                    float2 w2 = wkvS[ie * 49 + dy * 7 + dx];
                    float wv = w2.x * khS[rk + dx];
                    ka0 += (ie == 0) ? wv : 0.f;
                    ka1 += (ie == 1) ? wv : 0.f;
                    ka2 += (ie == 2) ? wv : 0.f;
                    ka3 += (ie == 3) ? wv : 0.f;
                    if (ie == ep) va += w2.y * vhS[rk + dx];
                }
            }
        }
        kAS[0*64+t] = ka0; kAS[1*64+t] = ka1; kAS[2*64+t] = ka2; kAS[3*64+t] = ka3;
        ovB[((size_t)(b * 64 + 32 + c)) * HWs + hw] = va;   // v plane
        __syncthreads();

        // ---- 8x8 circular convolution, own expert ----
        const float* qrow = &qAS[ep * 65];   // uniform -> broadcast
        const float* krow = &kAS[ep * 64];   // bijective -> 2 lanes/bank, free
        float oc = 0.f;
#pragma unroll
        for (int sy = 0; sy < 8; ++sy) {
            int ky = ((ly - sy) & 7) * 8;
#pragma unroll
            for (int sx = 0; sx < 8; ++sx)
                oc += qrow[sy * 8 + sx] * krow[ky + ((lx - sx) & 7)];
        }
        ovB[((size_t)(b * 64 + c)) * HWs + hw] = oc;        // o plane
    }
}

// K3a1: LN(o)*v -> ttv; bdy[r] = fpb + fpw.ttv  -> bdy planes.
// Only o[32] live (~50 VGPR). fpw staged at expert stride 1028 (bank offset 4e).
__global__ __launch_bounds__(256) void k_epiA1(
    const float* __restrict__ ovB, const int* __restrict__ eIdx,
    const float* __restrict__ lnw, const float* __restrict__ lnb,
    const float* __restrict__ fpw, const float* __restrict__ fpb,
    float* __restrict__ bdyPl)
{
    __shared__ __align__(16) float fpwS[4 * 1028];
    __shared__ float lnwS[132], lnbS[132], fpbS[132];
    const int tid = threadIdx.x;
    for (int i = tid; i < 4096; i += 256) fpwS[(i >> 10) * 1028 + (i & 1023)] = fpw[i];
    if (tid < 128) {
        lnwS[(tid >> 5) * 33 + (tid & 31)] = lnw[tid];
        lnbS[(tid >> 5) * 33 + (tid & 31)] = lnb[tid];
        fpbS[(tid >> 5) * 33 + (tid & 31)] = fpb[tid];
    }
    __syncthreads();

    const int p = blockIdx.x * 256 + tid;
    const int b = p >> 16;
    const int hw = p & 0xFFFF;
    const int ep = eIdx[p];

    float o[RK];
#pragma unroll
    for (int c = 0; c < RK; ++c) o[c] = ovB[((size_t)(b * 64 + c)) * HWs + hw];
    float mu = 0.f;
#pragma unroll
    for (int c = 0; c < RK; ++c) mu += o[c];
    mu *= (1.0f / RK);
    float var = 0.f;
#pragma unroll
    for (int c = 0; c < RK; ++c) { float d = o[c] - mu; var += d * d; }
    var *= (1.0f / RK);
    float inv = 1.0f / sqrtf(var + 1e-5f);
#pragma unroll
    for (int c = 0; c < RK; ++c)
        o[c] = ((o[c] - mu) * inv * lnwS[ep * 33 + c] + lnbS[ep * 33 + c])
               * ovB[((size_t)(b * 64 + 32 + c)) * HWs + hw];

#pragma unroll
    for (int r = 0; r < RK; ++r)
        bdyPl[((size_t)(b * RK + r)) * HWs + hw] =
            fpbS[ep * 33 + r] + dot32(&fpwS[ep * 1028 + r * 32], o);
}

// K3a2: z = p1w[ep].shared; u = silu(g z) * bdy -> u planes.
// p1w staged TRANSPOSED ([e][c][r], r contiguous, expert stride 2056) so the
// inner read is 8x b128 per c (4-addr broadcast) instead of 32x b32.
__global__ __launch_bounds__(256) void k_epiA2(
    const float* __restrict__ shr, const int* __restrict__ eIdx,
    const float* __restrict__ gVal, const float* __restrict__ p1w,
    const float* __restrict__ bdyPl, float* __restrict__ uPl)
{
    __shared__ __align__(16) float p1T[4 * 2056];
    const int tid = threadIdx.x;
    for (int i = tid; i < 8192; i += 256) {
        int r = i & 31, c = (i >> 5) & 63, e = i >> 11;
        p1T[e * 2056 + c * 32 + r] = p1w[(size_t)(e * 32 + r) * 64 + c];
    }
    __syncthreads();

    const int p = blockIdx.x * 256 + tid;
    const int b = p >> 16;
    const int hw = p & 0xFFFF;
    const int ep = eIdx[p];
    const float g = gVal[p];

    float z[RK];
#pragma unroll
    for (int r = 0; r < RK; ++r) z[r] = 0.f;
    for (int c = 0; c < DIMc; ++c) {
        float xc = shr[((size_t)(b * 64 + c)) * HWs + hw];
        const float4* w4 = (const float4*)&p1T[ep * 2056 + c * 32];
#pragma unroll
        for (int i = 0; i < 8; ++i) {
            float4 ww = w4[i];
            z[4*i]   += ww.x * xc; z[4*i+1] += ww.y * xc;
            z[4*i+2] += ww.z * xc; z[4*i+3] += ww.w * xc;
        }
    }
#pragma unroll
    for (int r = 0; r < RK; ++r) {
        float zz = z[r] * g;
        float gate = zz / (1.f + expf(-zz));
        uPl[((size_t)(b * RK + r)) * HWs + hw] =
            bdyPl[((size_t)(b * RK + r)) * HWs + hw] * gate;
    }
}

// K3b: out = outb + g^2*(outw.x) + g*(W2[ep].u), split into o-halves by
// blockIdx&1 so only acc[32] is live (~56 VGPR). Weight tiles staged per-half.
__global__ __launch_bounds__(256) void k_epiB(
    const float* __restrict__ x, const float* __restrict__ uPl,
    const int* __restrict__ eIdx, const float* __restrict__ gVal,
    const float* __restrict__ W2, const float* __restrict__ outw,
    const float* __restrict__ outb,
    float* __restrict__ out)
{
    __shared__ __align__(16) float owS[64 * 32];    // [c][o-half], uniform reads
    __shared__ __align__(16) float w2S[4 * 1028];   // [e][r*32+o-half]
    __shared__ float obS[32];
    const int tid = threadIdx.x;
    const int half = blockIdx.x & 1;

    for (int i = tid; i < 2048; i += 256) {
        int o = i & 31, c = i >> 5;
        owS[c * 32 + o] = outw[(half * 32 + o) * 64 + c];
    }
    for (int i = tid; i < 4096; i += 256) {
        int o = i & 31, r = (i >> 5) & 31, e = i >> 10;
        w2S[e * 1028 + r * 32 + o] = W2[e * 2048 + r * 64 + half * 32 + o];
    }
    if (tid < 32) obS[tid] = outb[half * 32 + tid];
    __syncthreads();

    const int p = (blockIdx.x >> 1) * 256 + tid;
    const int b = p >> 16;
    const int hw = p & 0xFFFF;
    const int ep = eIdx[p];
    const float g = gVal[p];
    const float g2 = g * g;

    float acc[RK];
#pragma unroll
    for (int o = 0; o < RK; ++o) acc[o] = obS[o];

    for (int c = 0; c < DIMc; ++c) {
        float xc = g2 * x[((size_t)(b * 64 + c)) * HWs + hw];
        const float4* w4 = (const float4*)&owS[c * 32];   // uniform broadcast
#pragma unroll
        for (int i = 0; i < 8; ++i) {
            float4 ww = w4[i];
            acc[4*i]   += ww.x * xc; acc[4*i+1] += ww.y * xc;
            acc[4*i+2] += ww.z * xc; acc[4*i+3] += ww.w * xc;
        }
    }
    for (int r = 0; r < RK; ++r) {
        float ur = g * uPl[((size_t)(b * RK + r)) * HWs + hw];
        const float4* w4 = (const float4*)&w2S[ep * 1028 + r * 32];  // 4-addr broadcast
#pragma unroll
        for (int i = 0; i < 8; ++i) {
            float4 ww = w4[i];
            acc[4*i]   += ww.x * ur; acc[4*i+1] += ww.y * ur;
            acc[4*i+2] += ww.z * ur; acc[4*i+3] += ww.w * ur;
        }
    }
#pragma unroll
    for (int o = 0; o < RK; ++o)
        out[((size_t)(b * 64 + half * 32 + o)) * HWs + hw] = acc[o];
}

extern "C" void kernel_launch(void* const* d_in, const int* in_sizes, int n_in,
                              void* d_out, int out_size, void* d_ws, size_t ws_size,
                              hipStream_t stream) {
    const float* x    = (const float*)d_in[0];
    const float* shr  = (const float*)d_in[1];
    const float* rw   = (const float*)d_in[2];
    const float* rb_  = (const float*)d_in[3];
    const float* p0w  = (const float*)d_in[4];
    const float* p1w  = (const float*)d_in[5];
    const float* p2w  = (const float*)d_in[6];
    const float* qw   = (const float*)d_in[7];
    const float* qdw  = (const float*)d_in[8];
    const float* qdb  = (const float*)d_in[9];
    const float* kvw  = (const float*)d_in[10];
    const float* kvdw = (const float*)d_in[11];
    const float* kvdb = (const float*)d_in[12];
    const float* lnw  = (const float*)d_in[13];
    const float* lnb  = (const float*)d_in[14];
    const float* fpw  = (const float*)d_in[15];
    const float* fpb  = (const float*)d_in[16];
    const float* outw = (const float*)d_in[17];
    const float* outb = (const float*)d_in[18];
    float* out = (float*)d_out;

    const int N = 4 * HWs;
    char* ws = (char*)d_ws;
    int*   eIdx  = (int*)ws;            ws += (size_t)N * sizeof(int);
    float* gV    = (float*)ws;          ws += (size_t)N * sizeof(float);
    float* qpre  = (float*)ws;          ws += (size_t)N * RK * sizeof(float);
    float* kvpre = (float*)ws;          ws += (size_t)N * 2 * RK * sizeof(float);
    float* W2    = (float*)ws;          ws += 8192 * sizeof(float);
    float* uPl   = qpre;    // qpre dead after k_patch
    float* bdyPl = kvpre;   // kvpre dead after k_patch (first 32 planes used)
    float* ovB   = out;     // o/v planes live in d_out until k_epiB overwrites

    k_router<<<N / 256, 256, 0, stream>>>(x, rw, rb_, p0w, qw, kvw, eIdx, gV, qpre, kvpre);
    k_w2<<<32, 256, 0, stream>>>(outw, p2w, W2);
    k_patch<<<4 * 32 * 32, 256, 0, stream>>>(eIdx, qpre, kvpre,
                                             qdw, qdb, kvdw, kvdb, ovB);
    k_epiA1<<<N / 256, 256, 0, stream>>>(ovB, eIdx, lnw, lnb, fpw, fpb, bdyPl);
    k_epiA2<<<N / 256, 256, 0, stream>>>(shr, eIdx, gV, p1w, bdyPl, uPl);
    k_epiB<<<2 * N / 256, 256, 0, stream>>>(x, uPl, eIdx, gV, W2, outw, outb, out);
}